// Round 1
// 399.702 us; speedup vs baseline: 1.0059x; 1.0059x over previous
//
#include <hip/hip_runtime.h>
#include <hip/hip_bf16.h>
#include <stdint.h>

// Problem constants (fixed by reference): N=8192, F=1024, F_=64, H=4
#define NN 8192
#define FF 1024
#define FD 64
#define NH 4
#define CC 256    // H*F_
#define MAXE 192  // max neighbors per row (mean ~34, max over 8192 rows ~56)

typedef __attribute__((ext_vector_type(8))) short short8;
typedef __attribute__((ext_vector_type(4))) short short4v;
typedef __attribute__((ext_vector_type(4))) float f32x4;

__device__ __forceinline__ short bf16_rne(float f) {
    union { float f; uint32_t u; } v; v.f = f;
    uint32_t r = (v.u + 0x7FFFu + ((v.u >> 16) & 1u)) >> 16;
    return (short)(r & 0xFFFFu);
}
__device__ __forceinline__ float bf2f(short s) {
    union { uint32_t u; float f; } v; v.u = ((uint32_t)(uint16_t)s) << 16;
    return v.f;
}

// ---------------------------------------------------------------------------
// Kernel 0a: W (H,F,F_) fp32 -> Wt[h][n][k] bf16 (transposed, contiguous k).
__global__ __launch_bounds__(256) void wt_kernel(const float* __restrict__ W,
                                                 short* __restrict__ Wt) {
    int gid = blockIdx.x * 256 + threadIdx.x;
    int k = gid & 1023;
    int n = (gid >> 10) & 63;
    int h = gid >> 16;
    Wt[gid] = bf16_rne(W[(h << 16) + k * 64 + n]);
}

// ---------------------------------------------------------------------------
// Kernel 0b: X fp32 -> bf16, float4-coalesced.
__global__ __launch_bounds__(256) void xb_kernel(const float* __restrict__ X,
                                                 short* __restrict__ Xb) {
    int gid = blockIdx.x * 256 + threadIdx.x;
    float4 v = ((const float4*)X)[gid];
    short4 o;
    o.x = bf16_rne(v.x); o.y = bf16_rne(v.y);
    o.z = bf16_rne(v.z); o.w = bf16_rne(v.w);
    ((short4*)Xb)[gid] = o;
}

// ---------------------------------------------------------------------------
// Kernel 1: feats = X·W per head, bf16 MFMA, fp32 acc. Tile BM=64/BN=64/BK=32.
// Epilogue: (a) feats stored as bf16 (halves smax gather traffic, feats fits
// per-XCD L2); (b) fused s_self/s_neigh via 16-lane xor-shuffle reduction.
__global__ __launch_bounds__(256) void gemm_kernel(const short* __restrict__ Xb,
                                                   const short* __restrict__ Wt,
                                                   const float* __restrict__ attn_a,
                                                   short* __restrict__ featb,
                                                   float* __restrict__ s_self,
                                                   float* __restrict__ s_neigh) {
    __shared__ short Xs[64 * 40];
    __shared__ short Ws[64 * 40];
    const int h  = blockIdx.x;
    const int m0 = blockIdx.y * 64;
    const int t  = threadIdx.x;
    const int wave = t >> 6, lane = t & 63;
    const int q = lane >> 4, nl = lane & 15;
    const int srow = t >> 2, sk8 = (t & 3) * 8;

    f32x4 acc0 = {0.f,0.f,0.f,0.f}, acc1 = {0.f,0.f,0.f,0.f};
    f32x4 acc2 = {0.f,0.f,0.f,0.f}, acc3 = {0.f,0.f,0.f,0.f};

    const short* Xp = Xb + (size_t)(m0 + srow) * FF + sk8;
    const short* Wp = Wt + (size_t)(h * 64 + srow) * FF + sk8;

    for (int k0 = 0; k0 < FF; k0 += 32) {
        short8 xv = *(const short8*)(Xp + k0);
        short8 wv = *(const short8*)(Wp + k0);
        *(short8*)(&Xs[srow * 40 + sk8]) = xv;
        *(short8*)(&Ws[srow * 40 + sk8]) = wv;
        __syncthreads();
        short8 a  = *(const short8*)(&Xs[(wave * 16 + nl) * 40 + q * 8]);
        short8 b0 = *(const short8*)(&Ws[( 0 + nl) * 40 + q * 8]);
        short8 b1 = *(const short8*)(&Ws[(16 + nl) * 40 + q * 8]);
        short8 b2 = *(const short8*)(&Ws[(32 + nl) * 40 + q * 8]);
        short8 b3 = *(const short8*)(&Ws[(48 + nl) * 40 + q * 8]);
        acc0 = __builtin_amdgcn_mfma_f32_16x16x32_bf16(a, b0, acc0, 0, 0, 0);
        acc1 = __builtin_amdgcn_mfma_f32_16x16x32_bf16(a, b1, acc1, 0, 0, 0);
        acc2 = __builtin_amdgcn_mfma_f32_16x16x32_bf16(a, b2, acc2, 0, 0, 0);
        acc3 = __builtin_amdgcn_mfma_f32_16x16x32_bf16(a, b3, acc3, 0, 0, 0);
        __syncthreads();
    }
    // C/D layout: col = nl (+16 per acc), row = m0 + wave*16 + q*4 + r
    const int row = m0 + wave * 16 + q * 4;
    const int colbase = h * 64 + nl;
    for (int r = 0; r < 4; ++r) {
        short* fr = featb + (size_t)(row + r) * CC + colbase;
        fr[ 0] = bf16_rne(acc0[r]);
        fr[16] = bf16_rne(acc1[r]);
        fr[32] = bf16_rne(acc2[r]);
        fr[48] = bf16_rne(acc3[r]);
    }
    // Fused s_self / s_neigh from fp32 accumulators (full precision).
    const float A0 = attn_a[h * 128 + nl],      A1 = attn_a[h * 128 + nl + 16];
    const float A2 = attn_a[h * 128 + nl + 32], A3 = attn_a[h * 128 + nl + 48];
    const float B0 = attn_a[h * 128 + 64 + nl],      B1 = attn_a[h * 128 + 64 + nl + 16];
    const float B2 = attn_a[h * 128 + 64 + nl + 32], B3 = attn_a[h * 128 + 64 + nl + 48];
    for (int r = 0; r < 4; ++r) {
        float ps = acc0[r] * A0 + acc1[r] * A1 + acc2[r] * A2 + acc3[r] * A3;
        float pn = acc0[r] * B0 + acc1[r] * B1 + acc2[r] * B2 + acc3[r] * B3;
        for (int off = 1; off < 16; off <<= 1) {
            ps += __shfl_xor(ps, off);
            pn += __shfl_xor(pn, off);
        }
        if (nl == 0) {
            s_self [h * NN + row + r] = ps;
            s_neigh[h * NN + row + r] = pn;
        }
    }
}

// ---------------------------------------------------------------------------
// Kernel 2 (FUSED scan+softmax+PV): block = row, wave = head.
// Phase A: scan this row of A (32 KB, nontemporal f32x4) -> compact neighbor
//          list in LDS. This streams 268 MB of A across the kernel; it
//          overlaps with other blocks' gather-latency phases (disjoint
//          resources: HBM stream vs L2 gather latency), removing the
//          previously-serialized standalone scan pass and the 12.6 MB
//          nbr/cnt global round-trip.
// Phase B: scores in registers, xor-shuffle max/sum. Chunk count is
//          (n+63)/64 (block-uniform): mean degree ~34 -> 1 chunk nearly
//          always, vs 3 unconditional chunks before.
// Phase C: PV gather, 4 neighbors/iter (16 lanes x short4 bf16 = 128 B per
//          neighbor row), cross-subgroup shuffle reduction at the end.
__global__ __launch_bounds__(256) void smax_kernel(const float* __restrict__ A,
                                                   const short* __restrict__ featb,
                                                   const float* __restrict__ s_self,
                                                   const float* __restrict__ s_neigh,
                                                   const float* __restrict__ bias,
                                                   float* __restrict__ out) {
    __shared__ int js[MAXE];
    __shared__ float ps[NH][MAXE];
    __shared__ int cs;
    const int row = blockIdx.x;
    const int t = threadIdx.x;
    if (t == 0) cs = 0;
    __syncthreads();

    // ---- Phase A: scan A row -> neighbor list ----
    const f32x4* A4 = (const f32x4*)(A + (size_t)row * NN);
    #pragma unroll
    for (int r = 0; r < 8; ++r) {
        int c4 = r * 256 + t;
        f32x4 v = __builtin_nontemporal_load(&A4[c4]);
        if (v.x > 0.5f) { int p = atomicAdd(&cs, 1); if (p < MAXE) js[p] = c4 * 4 + 0; }
        if (v.y > 0.5f) { int p = atomicAdd(&cs, 1); if (p < MAXE) js[p] = c4 * 4 + 1; }
        if (v.z > 0.5f) { int p = atomicAdd(&cs, 1); if (p < MAXE) js[p] = c4 * 4 + 2; }
        if (v.w > 0.5f) { int p = atomicAdd(&cs, 1); if (p < MAXE) js[p] = c4 * 4 + 3; }
    }
    __syncthreads();
    const int n = min(cs, MAXE);
    const int h = t >> 6, lane = t & 63;

    // ---- Phase B: scores ----
    const float si = s_self[h * NN + row];
    const float* snh = s_neigh + h * NN;

    float sc[3];
    #pragma unroll
    for (int i = 0; i < 3; ++i) sc[i] = -1e30f;
    const int nchunk = (n + 63) >> 6;   // 1..3, block-uniform
    for (int i = 0; i < nchunk; ++i) {
        int e = lane + 64 * i;
        if (e < n) {
            float s = si + snh[js[e]];
            sc[i] = s > 0.f ? s : 0.2f * s;
        }
    }
    float m = fmaxf(sc[0], fmaxf(sc[1], sc[2]));
    for (int off = 1; off < 64; off <<= 1) m = fmaxf(m, __shfl_xor(m, off));

    float dsum = 0.f;
    for (int i = 0; i < nchunk; ++i) {
        int e = lane + 64 * i;
        if (e < n) {
            float p = __expf(sc[i] - m);
            ps[h][e] = p;
            dsum += p;
        }
    }
    for (int off = 1; off < 64; off <<= 1) dsum += __shfl_xor(dsum, off);
    // ps[h][*] is written and read by wave h only -> no barrier needed.

    // ---- Phase C: PV gather ----
    const int sub = lane >> 4;   // neighbor sub-slot 0..3
    const int l16 = lane & 15;   // owns cols l16*4 .. l16*4+3
    const short* fb = featb + h * 64 + l16 * 4;
    f32x4 acc = {0.f, 0.f, 0.f, 0.f};
    #pragma unroll 2
    for (int e = sub; e < n; e += 4) {
        int j = js[e];
        float p = ps[h][e];
        short4v f = *(const short4v*)(fb + (size_t)j * CC);
        acc[0] = fmaf(p, bf2f(f.x), acc[0]);
        acc[1] = fmaf(p, bf2f(f.y), acc[1]);
        acc[2] = fmaf(p, bf2f(f.z), acc[2]);
        acc[3] = fmaf(p, bf2f(f.w), acc[3]);
    }
    #pragma unroll
    for (int k = 0; k < 4; ++k) {
        acc[k] += __shfl_xor(acc[k], 16);
        acc[k] += __shfl_xor(acc[k], 32);
    }
    if (sub == 0) {
        float rd = 1.0f / dsum;
        f32x4 o;
        #pragma unroll
        for (int k = 0; k < 4; ++k)
            o[k] = fmaxf(acc[k] * rd + bias[h * 64 + l16 * 4 + k], 0.f);
        *(f32x4*)(out + (size_t)row * CC + h * 64 + l16 * 4) = o;
    }
}

// ---------------------------------------------------------------------------
extern "C" void kernel_launch(void* const* d_in, const int* in_sizes, int n_in,
                              void* d_out, int out_size, void* d_ws, size_t ws_size,
                              hipStream_t stream) {
    const float* X      = (const float*)d_in[0];   // (8192, 1024)
    const float* A      = (const float*)d_in[1];   // (8192, 8192)
    const float* W      = (const float*)d_in[2];   // (4, 1024, 64)
    const float* attn_a = (const float*)d_in[3];   // (4, 128, 1)
    const float* bias   = (const float*)d_in[4];   // (4, 64)
    float* out = (float*)d_out;                    // (8192, 256)

    char* ws = (char*)d_ws;
    short* featb   = (short*)ws;                          //  4194304 B (bf16 feats)
    float* s_self  = (float*)(ws + 4194304);              //   131072 B
    float* s_neigh = (float*)(ws + 4325376);              //   131072 B
    short* Wt      = (short*)(ws + 4456448);              //   524288 B
    short* Xb      = (short*)(ws + 4980736);              // 16777216 B

    wt_kernel  <<<1024, 256, 0, stream>>>(W, Wt);
    xb_kernel  <<<8192, 256, 0, stream>>>(X, Xb);
    gemm_kernel<<<dim3(4, 128), 256, 0, stream>>>(Xb, Wt, attn_a, featb, s_self, s_neigh);
    smax_kernel<<<NN, 256, 0, stream>>>(A, featb, s_self, s_neigh, bias, out);
}